// Round 16
// baseline (231.976 us; speedup 1.0000x reference)
//
#include <hip/hip_runtime.h>
#include <math.h>

// Problem constants
constexpr int NND = 8192;           // N nodes
constexpr int FD  = 512;            // features
constexpr int HD  = 128;            // hidden
constexpr int ED  = 262144;         // edges
constexpr long long NF_ = (long long)NND * FD;      // 4,194,304
constexpr long long NN_ = (long long)NND * NND;     // 67,108,864

constexpr int SLOT = 72;            // bucket capacity; max row count ~56 (7-sigma)

// zero-fill quad partition of the dense adj region (units: float4 quads)
constexpr long long Z_K1 = 0;              // feature blocks: 24*262144 = 6,291,456 (6/16)
constexpr long long Z_KD = 6291456;        // scatter blocks:  8*262144 = 2,097,152 (2/16)
constexpr long long Z_KE = 8388608;        // kE: 6*1048576 = 6,291,456 (6/16)
constexpr long long Z_KF = 14680064;       // kF: 8*262144 = 2,097,152 (ends 16,777,216)

constexpr int GEMMB = 256;                 // GEMM blocks [0,256): 32 rows each
constexpr int SCAT_BASE = GEMMB;           // scatter blocks [256,1280)
constexpr int FEAT_BASE = GEMMB + 1024;    // feature blocks [1280,2304)

// nontemporal float4 store (bypasses L2 allocation; for never-re-read data)
typedef float f4nt __attribute__((ext_vector_type(4)));
__device__ __forceinline__ void nt_store(float4* p, float x, float y, float z, float w) {
    f4nt v = {x, y, z, w};
    __builtin_nontemporal_store(v, (f4nt*)p);
}
__device__ __forceinline__ void nt_zero(float4* p) { nt_store(p, 0.f, 0.f, 0.f, 0.f); }

// ctrl words: [4]=ticketF, [5]=ticketZ, [8..9]=float lo/hi (written by kF)

// K0: zero cnt + ctrl.
__global__ void k0_init(int* __restrict__ cnt, unsigned* __restrict__ ctrl) {
    int t = blockIdx.x * 256 + threadIdx.x;
    if (t < NND) cnt[t] = 0;
    if (t < 16) ctrl[t] = 0u;
}

// K1: blocks [0,256)     = fp32 GEMM xw = x@W_enc; W from global (L1-hot),
//                          wave-private transposed x-tile in LDS; 2x8 thread tile;
//     blocks [256,1280)  = edge scatter into row buckets + 2/16 adj fill;
//     blocks [1280,2304) = feature mask (4 quads/thread) + 6/16 adj fill.
__global__ __launch_bounds__(256) void k1_mega(const float* __restrict__ x,
                                               const float* __restrict__ W,
                                               const float* __restrict__ mask_u,
                                               const int* __restrict__ row,
                                               const int* __restrict__ col,
                                               float* __restrict__ out,
                                               float* __restrict__ xw,
                                               int* __restrict__ cnt,
                                               int* __restrict__ slot) {
    __shared__ float Xt[4][32][8];      // 4 KB: per-wave transposed x k-tile
    int tid = threadIdx.x;
    if (blockIdx.x < GEMMB) {
        // ---- GEMM: block = 32 rows (4 waves x 8 rows); thread = 2 rows x 8 cols
        // W read from global per kk (VMEM pipe, L1-hot across 256 blocks);
        // x staged per-wave in LDS, transposed, read as conflict-free b64.
        int bid = blockIdx.x;
        int wv = tid >> 6;              // wave 0..3
        int lane = tid & 63;
        int tx = lane & 15;             // cols tx*8 .. +7
        int ty = lane >> 4;             // rows ty*2 .. +1 (of this wave's 8)
        int m0w = bid * 32 + wv * 8;    // wave's first row
        int rs = lane & 7;              // staging row
        int kq = lane >> 3;             // staging k-quad [0,8)
        float a0[8] = {0.f, 0.f, 0.f, 0.f, 0.f, 0.f, 0.f, 0.f};
        float a1[8] = {0.f, 0.f, 0.f, 0.f, 0.f, 0.f, 0.f, 0.f};
        for (int kt = 0; kt < FD; kt += 32) {
            // stage x tile: 8 rows x 32 k, transposed -> Xt[wv][kk][r]
            float4 xv = *(const float4*)(x + (long long)(m0w + rs) * FD + kt + kq * 4);
            Xt[wv][kq * 4 + 0][rs] = xv.x;
            Xt[wv][kq * 4 + 1][rs] = xv.y;
            Xt[wv][kq * 4 + 2][rs] = xv.z;
            Xt[wv][kq * 4 + 3][rs] = xv.w;
            __syncthreads();
#pragma unroll 8
            for (int kk = 0; kk < 32; ++kk) {
                const float* wr = W + (long long)(kt + kk) * HD + tx * 8;
                float4 b0 = *(const float4*)wr;
                float4 b1 = *(const float4*)(wr + 4);
                float2 xr = *(const float2*)&Xt[wv][kk][ty * 2];
                float bs[8] = {b0.x, b0.y, b0.z, b0.w, b1.x, b1.y, b1.z, b1.w};
#pragma unroll
                for (int ci = 0; ci < 8; ++ci) {
                    a0[ci] = fmaf(xr.x, bs[ci], a0[ci]);
                    a1[ci] = fmaf(xr.y, bs[ci], a1[ci]);
                }
            }
            __syncthreads();
        }
        float* o0 = xw + (long long)(m0w + ty * 2) * HD + tx * 8;
        float* o1 = o0 + HD;
        *(float4*)o0 = make_float4(a0[0], a0[1], a0[2], a0[3]);
        *(float4*)(o0 + 4) = make_float4(a0[4], a0[5], a0[6], a0[7]);
        *(float4*)o1 = make_float4(a1[0], a1[1], a1[2], a1[3]);
        *(float4*)(o1 + 4) = make_float4(a1[4], a1[5], a1[6], a1[7]);
    } else if (blockIdx.x < FEAT_BASE) {
        // ---- scatter: one edge per thread into its row bucket; +2/16 fill ----
        int e = (blockIdx.x - SCAT_BASE) * 256 + tid;   // 0 .. 262143
        int r = row[e];
        int pos = atomicAdd(&cnt[r], 1);
        slot[r * SLOT + pos] = (e << 13) | col[e];
        float4* zq = (float4*)(out + NF_);
#pragma unroll
        for (int j = 0; j < 8; ++j)
            nt_zero(&zq[Z_KD + e + (long long)j * ED]);
    } else {
        int fid = (blockIdx.x - FEAT_BASE) * 256 + tid;   // 0 .. 262143
        // column-quad = fid & 127 (stride 262144 is a multiple of 128)
        int c4 = (fid & 127) * 4;
        float kx = (mask_u[c4 + 0] < 0.2f) ? 0.f : 1.f;
        float ky = (mask_u[c4 + 1] < 0.2f) ? 0.f : 1.f;
        float kz = (mask_u[c4 + 2] < 0.2f) ? 0.f : 1.f;
        float kw = (mask_u[c4 + 3] < 0.2f) ? 0.f : 1.f;
        const float4* xq = (const float4*)x;
        float4* oq = (float4*)out;
#pragma unroll
        for (int j = 0; j < 4; ++j) {
            long long q = fid + (long long)j * 262144;
            float4 xv = xq[q];
            nt_store(&oq[q], xv.x * kx, xv.y * ky, xv.z * kz, xv.w * kw);
        }
        // 6/16 of the dense adj zero-fill
        float4* zq = (float4*)(out + NF_);
#pragma unroll
        for (int j = 0; j < 24; ++j)
            nt_zero(&zq[Z_K1 + fid + (long long)j * 262144]);
    }
}

// K_E: agg[i] = sum over bucket(i) of xw[col]; relu; u=agg@W1, v=agg@W2; +6/16 fill.
__global__ __launch_bounds__(128) void kE_spmm_uv(const float* __restrict__ xw,
                                                  const int* __restrict__ cnt,
                                                  const int* __restrict__ slot,
                                                  const float* __restrict__ Wedge,
                                                  float* __restrict__ u,
                                                  float* __restrict__ v,
                                                  float4* __restrict__ zq) {
    int i = blockIdx.x, t = threadIdx.x;
    int n = cnt[i];
    const int* sp = slot + i * SLOT;
    float acc = 0.f;
    int j = 0;
    for (; j + 4 <= n; j += 4) {
        int c0 = sp[j] & 8191, c1 = sp[j + 1] & 8191;
        int c2 = sp[j + 2] & 8191, c3 = sp[j + 3] & 8191;
        float v0 = xw[(long long)c0 * HD + t];
        float v1 = xw[(long long)c1 * HD + t];
        float v2 = xw[(long long)c2 * HD + t];
        float v3 = xw[(long long)c3 * HD + t];
        acc += v0; acc += v1; acc += v2; acc += v3;
    }
    for (; j < n; ++j) acc += xw[(long long)(sp[j] & 8191) * HD + t];
    acc = fmaxf(acc, 0.f);

    float up = acc * Wedge[t];
    float vp = acc * Wedge[HD + t];
#pragma unroll
    for (int off = 32; off > 0; off >>= 1) {
        up += __shfl_down(up, off);
        vp += __shfl_down(vp, off);
    }
    __shared__ float su[2], sv[2];
    int wid = t >> 6;
    if ((t & 63) == 0) { su[wid] = up; sv[wid] = vp; }
    __syncthreads();
    if (t == 0) { u[i] = su[0] + su[1]; v[i] = sv[0] + sv[1]; }

    // 6/16 of the dense adj zero-fill
    long long ft = (long long)i * 128 + t;
#pragma unroll
    for (int jj = 0; jj < 6; ++jj)
        nt_zero(&zq[Z_KE + ft + (long long)jj * 1048576]);
}

// K_F: edge-logit min/max only (logits recomputed in kZ, never stored);
// +2/16 fill; per-block partials; last block publishes lo/hi to ctrl[8..9].
__global__ __launch_bounds__(256) void kF_minmax(const int* __restrict__ row,
                                                 const int* __restrict__ col,
                                                 const float* __restrict__ u,
                                                 const float* __restrict__ v,
                                                 const float* __restrict__ b_edge,
                                                 float* __restrict__ pmn,
                                                 float* __restrict__ pmx,
                                                 unsigned* __restrict__ ctrl,
                                                 float4* __restrict__ zq) {
    int gid = blockIdx.x * 256 + threadIdx.x;
    float el = u[row[gid]] + v[col[gid]] + b_edge[0];

#pragma unroll
    for (int j = 0; j < 8; ++j)
        nt_zero(&zq[Z_KF + gid + (long long)j * ED]);

    float mn = el, mx = el;
#pragma unroll
    for (int off = 32; off > 0; off >>= 1) {
        mn = fminf(mn, __shfl_xor(mn, off));
        mx = fmaxf(mx, __shfl_xor(mx, off));
    }
    __shared__ float smn[4], smx[4];
    __shared__ unsigned tkt;
    int w = threadIdx.x >> 6;
    if ((threadIdx.x & 63) == 0) { smn[w] = mn; smx[w] = mx; }
    __syncthreads();
    if (threadIdx.x == 0) {
        pmn[blockIdx.x] = fminf(fminf(smn[0], smn[1]), fminf(smn[2], smn[3]));
        pmx[blockIdx.x] = fmaxf(fmaxf(smx[0], smx[1]), fmaxf(smx[2], smx[3]));
        __threadfence();
        tkt = atomicAdd(&ctrl[4], 1u);
    }
    __syncthreads();
    if (tkt == gridDim.x - 1) {
        __threadfence();
        int t = threadIdx.x;
        float4 a = ((const float4*)pmn)[t];
        float4 b = ((const float4*)pmx)[t];
        float m2 = fminf(fminf(a.x, a.y), fminf(a.z, a.w));
        float x2 = fmaxf(fmaxf(b.x, b.y), fmaxf(b.z, b.w));
#pragma unroll
        for (int off = 32; off > 0; off >>= 1) {
            m2 = fminf(m2, __shfl_xor(m2, off));
            x2 = fmaxf(x2, __shfl_xor(x2, off));
        }
        __shared__ float rmn[4], rmx[4];
        if ((t & 63) == 0) { rmn[t >> 6] = m2; rmx[t >> 6] = x2; }
        __syncthreads();
        if (t == 0) {
            float* flh = (float*)&ctrl[8];
            flh[0] = fminf(fminf(rmn[0], rmn[1]), fminf(rmn[2], rmn[3]));
            flh[1] = fmaxf(fmaxf(rmx[0], rmx[1]), fmaxf(rmx[2], rmx[3]));
        }
    }
}

// K_Z: parallel patch. Block b owns rows [8b, 8b+8); per-row buckets in LDS;
// last-edge-wins; el recomputed as u[r]+v[c]+b (bit-identical to kF's form).
__global__ __launch_bounds__(256) void kZ_patch(const int* __restrict__ cnt,
                                                const int* __restrict__ slot,
                                                const float* __restrict__ u,
                                                const float* __restrict__ v,
                                                const float* __restrict__ b_edge,
                                                const float* __restrict__ noise,
                                                float* __restrict__ adj,
                                                int* __restrict__ pcu,
                                                int* __restrict__ pcz,
                                                unsigned* __restrict__ ctrl,
                                                float* __restrict__ rate) {
    const int tid = threadIdx.x;
    const int b = blockIdx.x;
    __shared__ int skey[8 * SLOT];
    __shared__ int scnt[8];
    __shared__ float su_[8];
    if (tid < 8) {
        scnt[tid] = cnt[b * 8 + tid];
        su_[tid] = u[b * 8 + tid];
    }
    __syncthreads();
#pragma unroll
    for (int rl = 0; rl < 8; ++rl) {
        int n = scnt[rl];
        for (int i = tid; i < n; i += 256)
            skey[rl * SLOT + i] = slot[(b * 8 + rl) * SLOT + i];
    }
    __syncthreads();

    const float* flh = (const float*)&ctrl[8];
    const float lo = flh[0];
    const float hi = flh[1];
    const float kk = 0.3f / (hi - lo);          // ub=0.3, lb=0
    const float be = b_edge[0];

    int uniq = 0, nzc = 0;
#pragma unroll
    for (int rl = 0; rl < 8; ++rl) {
        int n = scnt[rl];
        const int* kp = skey + rl * SLOT;
        for (int i = tid; i < n; i += 256) {
            int key = kp[i];
            int c = key & 8191;
            // last-edge-wins: winner iff no same-col key with larger e in this row
            bool win = true;
            for (int j = 0; j < n; ++j) {
                int kj = kp[j];
                if ((kj & 8191) == c && kj > key) { win = false; break; }
            }
            if (!win) continue;
            ++uniq;
            float el = su_[rl] + v[c] + be;     // == kF's logit, bit-identical
            float pr = kk * (el - lo);
            float lp = logf(pr + 1e-10f) - log1pf(1e-10f - pr);
            float nz = noise[(long long)(b * 8 + rl) * NND + c];
            float lg = logf(nz) - log1pf(-nz);
            if ((lp + lg) <= 0.f) {             // hard==0 -> adj cell = 1
                ++nzc;
                adj[(long long)(b * 8 + rl) * NND + c] = 1.0f;
            }
        }
    }

    // block reduce
#pragma unroll
    for (int off = 32; off > 0; off >>= 1) {
        uniq += __shfl_down(uniq, off);
        nzc  += __shfl_down(nzc, off);
    }
    __shared__ int scu[4], scz[4];
    __shared__ unsigned tkt;
    int wd = tid >> 6;
    if ((tid & 63) == 0) { scu[wd] = uniq; scz[wd] = nzc; }
    __syncthreads();
    if (tid == 0) {
        pcu[b] = scu[0] + scu[1] + scu[2] + scu[3];
        pcz[b] = scz[0] + scz[1] + scz[2] + scz[3];
        __threadfence();
        tkt = atomicAdd(&ctrl[5], 1u);
    }
    __syncthreads();
    if (tkt == gridDim.x - 1) {
        __threadfence();
        int t = tid;
        int4 a = ((const int4*)pcu)[t];
        int4 bq = ((const int4*)pcz)[t];
        int cu = a.x + a.y + a.z + a.w;
        int cz = bq.x + bq.y + bq.z + bq.w;
#pragma unroll
        for (int off = 32; off > 0; off >>= 1) {
            cu += __shfl_down(cu, off);
            cz += __shfl_down(cz, off);
        }
        __shared__ int rcu[4], rcz[4];
        if ((t & 63) == 0) { rcu[t >> 6] = cu; rcz[t >> 6] = cz; }
        __syncthreads();
        if (t == 0)
            rate[0] = (float)(rcz[0] + rcz[1] + rcz[2] + rcz[3]) /
                      (float)(rcu[0] + rcu[1] + rcu[2] + rcu[3]);
    }
}

extern "C" void kernel_launch(void* const* d_in, const int* in_sizes, int n_in,
                              void* d_out, int out_size, void* d_ws, size_t ws_size,
                              hipStream_t stream) {
    const float* x     = (const float*)d_in[0];
    const int*   row   = (const int*)d_in[1];
    const int*   col   = (const int*)d_in[2];
    const float* Wenc  = (const float*)d_in[3];
    const float* Wedge = (const float*)d_in[4];
    const float* bedge = (const float*)d_in[5];
    const float* noise = (const float*)d_in[6];
    const float* masku = (const float*)d_in[7];
    float* out = (float*)d_out;

    // workspace layout (~6.67 MB)
    char* ws = (char*)d_ws;
    float* xw   = (float*)(ws);                 // 4,194,304 B
    int*   slot = (int*)  (ws + 4194304);       // 8192*72*4 = 2,359,296 B
    float* u    = (float*)(ws + 6553600);       // 32 KB
    float* v    = (float*)(ws + 6586368);       // 32 KB
    int*   cnt  = (int*)  (ws + 6619136);       // 32 KB
    int*   pcu  = (int*)  (ws + 6651904);       // 4 KB
    int*   pcz  = (int*)  (ws + 6656000);       // 4 KB
    float* pmn  = (float*)(ws + 6660096);       // 4 KB
    float* pmx  = (float*)(ws + 6664192);       // 4 KB
    unsigned* ctrl = (unsigned*)(ws + 6668288); // 64 B

    float4* zq  = (float4*)(out + NF_);
    float*  adj = out + NF_;
    float* rate = out + NF_ + NN_;

    k0_init<<<32, 256, 0, stream>>>(cnt, ctrl);
    k1_mega<<<GEMMB + 1024 + 1024, 256, 0, stream>>>(x, Wenc, masku, row, col,
                                                     out, xw, cnt, slot);
    kE_spmm_uv<<<8192, 128, 0, stream>>>(xw, cnt, slot, Wedge, u, v, zq);
    kF_minmax<<<1024, 256, 0, stream>>>(row, col, u, v, bedge, pmn, pmx, ctrl, zq);
    kZ_patch<<<1024, 256, 0, stream>>>(cnt, slot, u, v, bedge, noise, adj,
                                       pcu, pcz, ctrl, rate);
}

// Round 17
// 197.799 us; speedup vs baseline: 1.1728x; 1.1728x over previous
//
#include <hip/hip_runtime.h>
#include <math.h>

// Problem constants
constexpr int NND = 8192;           // N nodes
constexpr int FD  = 512;            // features
constexpr int HD  = 128;            // hidden
constexpr int ED  = 262144;         // edges
constexpr long long NF_ = (long long)NND * FD;      // 4,194,304
constexpr long long NN_ = (long long)NND * NND;     // 67,108,864

constexpr int SLOT = 72;            // bucket capacity; max row count ~56 (7-sigma)

// zero-fill quad partition of the dense adj region (units: float4 quads)
constexpr long long Z_K1 = 0;              // feature blocks: 24*262144 = 6,291,456 (6/16)
constexpr long long Z_KD = 6291456;        // scatter blocks:  8*262144 = 2,097,152 (2/16)
constexpr long long Z_KE = 8388608;        // kE: 6*1048576 = 6,291,456 (6/16)
constexpr long long Z_KF = 14680064;       // kF: 8*262144 = 2,097,152 (ends 16,777,216)

constexpr int GEMMB = 256;                 // GEMM blocks [0,256): 32 rows each
constexpr int SCAT_BASE = GEMMB;           // scatter blocks [256,1280)
constexpr int FEAT_BASE = GEMMB + 1024;    // feature blocks [1280,2304)

// nontemporal float4 store (bypasses L2 allocation; for never-re-read data)
typedef float f4nt __attribute__((ext_vector_type(4)));
__device__ __forceinline__ void nt_store(float4* p, float x, float y, float z, float w) {
    f4nt v = {x, y, z, w};
    __builtin_nontemporal_store(v, (f4nt*)p);
}
__device__ __forceinline__ void nt_zero(float4* p) { nt_store(p, 0.f, 0.f, 0.f, 0.f); }

// ctrl words: [4]=ticketF, [5]=ticketZ, [8..9]=float lo/hi (written by kF)

// K0: zero cnt + ctrl.
__global__ void k0_init(int* __restrict__ cnt, unsigned* __restrict__ ctrl) {
    int t = blockIdx.x * 256 + threadIdx.x;
    if (t < NND) cnt[t] = 0;
    if (t < 16) ctrl[t] = 0u;
}

// K1: blocks [0,256)     = fp32 GEMM xw = x@W_enc, LDS k-tiles, 2x8 thread tile,
//                          broadcast-friendly lane mapping (16 tx x 16 ty);
//     blocks [256,1280)  = edge scatter into row buckets + 2/16 adj fill;
//     blocks [1280,2304) = feature mask (4 quads/thread) + 6/16 adj fill.
__global__ __launch_bounds__(256) void k1_mega(const float* __restrict__ x,
                                               const float* __restrict__ W,
                                               const float* __restrict__ mask_u,
                                               const int* __restrict__ row,
                                               const int* __restrict__ col,
                                               float* __restrict__ out,
                                               float* __restrict__ xw,
                                               int* __restrict__ cnt,
                                               int* __restrict__ slot) {
    __shared__ float Wt[32 * 128];      // 16 KB: W k-tile [kk][col]
    __shared__ float Xt[32][32];        //  4 KB: x k-tile TRANSPOSED [kk][row]
    int tid = threadIdx.x;
    if (blockIdx.x < GEMMB) {
        // ---- GEMM: block = 32 rows x 128 cols; thread = 2 rows x 8 cols ----
        // per kk: 2 b128 W reads at 16 distinct addrs (4-way broadcast) +
        //         1 b64 X read at 16 distinct addrs -> ~10 LDS cy / 16 fma.
        int bid = blockIdx.x;
        int tx = tid & 15;              // cols tx*8 .. +7
        int ty = tid >> 4;              // rows ty*2, ty*2+1
        int m0 = bid * 32;
        float a0[8] = {0.f, 0.f, 0.f, 0.f, 0.f, 0.f, 0.f, 0.f};
        float a1[8] = {0.f, 0.f, 0.f, 0.f, 0.f, 0.f, 0.f, 0.f};
        int rs = tid >> 3;              // staging row [0,32)
        int kq = tid & 7;               // staging k-quad [0,8)
        for (int kt = 0; kt < FD; kt += 32) {
            // stage W tile: contiguous 32*128 floats = 1024 float4, 4/thread
            const float4* Wq = (const float4*)(W + (long long)kt * HD);
            float4* Wtq = (float4*)Wt;
#pragma unroll
            for (int j = 0; j < 4; ++j)
                Wtq[tid + j * 256] = Wq[tid + j * 256];
            // stage x tile transposed: 32 rows x 32 k -> Xt[kk][r], 1 quad/thread
            float4 xv = *(const float4*)(x + (long long)(m0 + rs) * FD + kt + kq * 4);
            Xt[kq * 4 + 0][rs] = xv.x;
            Xt[kq * 4 + 1][rs] = xv.y;
            Xt[kq * 4 + 2][rs] = xv.z;
            Xt[kq * 4 + 3][rs] = xv.w;
            __syncthreads();
#pragma unroll 8
            for (int kk = 0; kk < 32; ++kk) {
                float4 b0 = *(const float4*)&Wt[kk * 128 + tx * 8];
                float4 b1 = *(const float4*)&Wt[kk * 128 + tx * 8 + 4];
                float2 xr = *(const float2*)&Xt[kk][ty * 2];
                float bs[8] = {b0.x, b0.y, b0.z, b0.w, b1.x, b1.y, b1.z, b1.w};
#pragma unroll
                for (int ci = 0; ci < 8; ++ci) {
                    a0[ci] = fmaf(xr.x, bs[ci], a0[ci]);
                    a1[ci] = fmaf(xr.y, bs[ci], a1[ci]);
                }
            }
            __syncthreads();
        }
        float* o0 = xw + (long long)(m0 + ty * 2) * HD + tx * 8;
        float* o1 = o0 + HD;
        *(float4*)o0 = make_float4(a0[0], a0[1], a0[2], a0[3]);
        *(float4*)(o0 + 4) = make_float4(a0[4], a0[5], a0[6], a0[7]);
        *(float4*)o1 = make_float4(a1[0], a1[1], a1[2], a1[3]);
        *(float4*)(o1 + 4) = make_float4(a1[4], a1[5], a1[6], a1[7]);
    } else if (blockIdx.x < FEAT_BASE) {
        // ---- scatter: one edge per thread into its row bucket; +2/16 fill ----
        int e = (blockIdx.x - SCAT_BASE) * 256 + tid;   // 0 .. 262143
        int r = row[e];
        int pos = atomicAdd(&cnt[r], 1);
        slot[r * SLOT + pos] = (e << 13) | col[e];
        float4* zq = (float4*)(out + NF_);
#pragma unroll
        for (int j = 0; j < 8; ++j)
            nt_zero(&zq[Z_KD + e + (long long)j * ED]);
    } else {
        int fid = (blockIdx.x - FEAT_BASE) * 256 + tid;   // 0 .. 262143
        // column-quad = fid & 127 (stride 262144 is a multiple of 128)
        int c4 = (fid & 127) * 4;
        float kx = (mask_u[c4 + 0] < 0.2f) ? 0.f : 1.f;
        float ky = (mask_u[c4 + 1] < 0.2f) ? 0.f : 1.f;
        float kz = (mask_u[c4 + 2] < 0.2f) ? 0.f : 1.f;
        float kw = (mask_u[c4 + 3] < 0.2f) ? 0.f : 1.f;
        const float4* xq = (const float4*)x;
        float4* oq = (float4*)out;
#pragma unroll
        for (int j = 0; j < 4; ++j) {
            long long q = fid + (long long)j * 262144;
            float4 xv = xq[q];
            nt_store(&oq[q], xv.x * kx, xv.y * ky, xv.z * kz, xv.w * kw);
        }
        // 6/16 of the dense adj zero-fill
        float4* zq = (float4*)(out + NF_);
#pragma unroll
        for (int j = 0; j < 24; ++j)
            nt_zero(&zq[Z_K1 + fid + (long long)j * 262144]);
    }
}

// K_E: agg[i] = sum over bucket(i) of xw[col]; relu; u=agg@W1, v=agg@W2; +6/16 fill.
__global__ __launch_bounds__(128) void kE_spmm_uv(const float* __restrict__ xw,
                                                  const int* __restrict__ cnt,
                                                  const int* __restrict__ slot,
                                                  const float* __restrict__ Wedge,
                                                  float* __restrict__ u,
                                                  float* __restrict__ v,
                                                  float4* __restrict__ zq) {
    int i = blockIdx.x, t = threadIdx.x;
    int n = cnt[i];
    const int* sp = slot + i * SLOT;
    float acc = 0.f;
    int j = 0;
    for (; j + 4 <= n; j += 4) {
        int c0 = sp[j] & 8191, c1 = sp[j + 1] & 8191;
        int c2 = sp[j + 2] & 8191, c3 = sp[j + 3] & 8191;
        float v0 = xw[(long long)c0 * HD + t];
        float v1 = xw[(long long)c1 * HD + t];
        float v2 = xw[(long long)c2 * HD + t];
        float v3 = xw[(long long)c3 * HD + t];
        acc += v0; acc += v1; acc += v2; acc += v3;
    }
    for (; j < n; ++j) acc += xw[(long long)(sp[j] & 8191) * HD + t];
    acc = fmaxf(acc, 0.f);

    float up = acc * Wedge[t];
    float vp = acc * Wedge[HD + t];
#pragma unroll
    for (int off = 32; off > 0; off >>= 1) {
        up += __shfl_down(up, off);
        vp += __shfl_down(vp, off);
    }
    __shared__ float su[2], sv[2];
    int wid = t >> 6;
    if ((t & 63) == 0) { su[wid] = up; sv[wid] = vp; }
    __syncthreads();
    if (t == 0) { u[i] = su[0] + su[1]; v[i] = sv[0] + sv[1]; }

    // 6/16 of the dense adj zero-fill
    long long ft = (long long)i * 128 + t;
#pragma unroll
    for (int jj = 0; jj < 6; ++jj)
        nt_zero(&zq[Z_KE + ft + (long long)jj * 1048576]);
}

// K_F: edge-logit min/max only (logits recomputed in kZ, never stored);
// +2/16 fill; per-block partials; last block publishes lo/hi to ctrl[8..9].
__global__ __launch_bounds__(256) void kF_minmax(const int* __restrict__ row,
                                                 const int* __restrict__ col,
                                                 const float* __restrict__ u,
                                                 const float* __restrict__ v,
                                                 const float* __restrict__ b_edge,
                                                 float* __restrict__ pmn,
                                                 float* __restrict__ pmx,
                                                 unsigned* __restrict__ ctrl,
                                                 float4* __restrict__ zq) {
    int gid = blockIdx.x * 256 + threadIdx.x;
    float el = u[row[gid]] + v[col[gid]] + b_edge[0];

#pragma unroll
    for (int j = 0; j < 8; ++j)
        nt_zero(&zq[Z_KF + gid + (long long)j * ED]);

    float mn = el, mx = el;
#pragma unroll
    for (int off = 32; off > 0; off >>= 1) {
        mn = fminf(mn, __shfl_xor(mn, off));
        mx = fmaxf(mx, __shfl_xor(mx, off));
    }
    __shared__ float smn[4], smx[4];
    __shared__ unsigned tkt;
    int w = threadIdx.x >> 6;
    if ((threadIdx.x & 63) == 0) { smn[w] = mn; smx[w] = mx; }
    __syncthreads();
    if (threadIdx.x == 0) {
        pmn[blockIdx.x] = fminf(fminf(smn[0], smn[1]), fminf(smn[2], smn[3]));
        pmx[blockIdx.x] = fmaxf(fmaxf(smx[0], smx[1]), fmaxf(smx[2], smx[3]));
        __threadfence();
        tkt = atomicAdd(&ctrl[4], 1u);
    }
    __syncthreads();
    if (tkt == gridDim.x - 1) {
        __threadfence();
        int t = threadIdx.x;
        float4 a = ((const float4*)pmn)[t];
        float4 b = ((const float4*)pmx)[t];
        float m2 = fminf(fminf(a.x, a.y), fminf(a.z, a.w));
        float x2 = fmaxf(fmaxf(b.x, b.y), fmaxf(b.z, b.w));
#pragma unroll
        for (int off = 32; off > 0; off >>= 1) {
            m2 = fminf(m2, __shfl_xor(m2, off));
            x2 = fmaxf(x2, __shfl_xor(x2, off));
        }
        __shared__ float rmn[4], rmx[4];
        if ((t & 63) == 0) { rmn[t >> 6] = m2; rmx[t >> 6] = x2; }
        __syncthreads();
        if (t == 0) {
            float* flh = (float*)&ctrl[8];
            flh[0] = fminf(fminf(rmn[0], rmn[1]), fminf(rmn[2], rmn[3]));
            flh[1] = fmaxf(fmaxf(rmx[0], rmx[1]), fmaxf(rmx[2], rmx[3]));
        }
    }
}

// K_Z: parallel patch. Block b owns rows [8b, 8b+8); per-row buckets in LDS;
// last-edge-wins; el recomputed as u[r]+v[c]+b (bit-identical to kF's form).
__global__ __launch_bounds__(256) void kZ_patch(const int* __restrict__ cnt,
                                                const int* __restrict__ slot,
                                                const float* __restrict__ u,
                                                const float* __restrict__ v,
                                                const float* __restrict__ b_edge,
                                                const float* __restrict__ noise,
                                                float* __restrict__ adj,
                                                int* __restrict__ pcu,
                                                int* __restrict__ pcz,
                                                unsigned* __restrict__ ctrl,
                                                float* __restrict__ rate) {
    const int tid = threadIdx.x;
    const int b = blockIdx.x;
    __shared__ int skey[8 * SLOT];
    __shared__ int scnt[8];
    __shared__ float su_[8];
    if (tid < 8) {
        scnt[tid] = cnt[b * 8 + tid];
        su_[tid] = u[b * 8 + tid];
    }
    __syncthreads();
#pragma unroll
    for (int rl = 0; rl < 8; ++rl) {
        int n = scnt[rl];
        for (int i = tid; i < n; i += 256)
            skey[rl * SLOT + i] = slot[(b * 8 + rl) * SLOT + i];
    }
    __syncthreads();

    const float* flh = (const float*)&ctrl[8];
    const float lo = flh[0];
    const float hi = flh[1];
    const float kk = 0.3f / (hi - lo);          // ub=0.3, lb=0
    const float be = b_edge[0];

    int uniq = 0, nzc = 0;
#pragma unroll
    for (int rl = 0; rl < 8; ++rl) {
        int n = scnt[rl];
        const int* kp = skey + rl * SLOT;
        for (int i = tid; i < n; i += 256) {
            int key = kp[i];
            int c = key & 8191;
            // last-edge-wins: winner iff no same-col key with larger e in this row
            bool win = true;
            for (int j = 0; j < n; ++j) {
                int kj = kp[j];
                if ((kj & 8191) == c && kj > key) { win = false; break; }
            }
            if (!win) continue;
            ++uniq;
            float el = su_[rl] + v[c] + be;     // == kF's logit, bit-identical
            float pr = kk * (el - lo);
            float lp = logf(pr + 1e-10f) - log1pf(1e-10f - pr);
            float nz = noise[(long long)(b * 8 + rl) * NND + c];
            float lg = logf(nz) - log1pf(-nz);
            if ((lp + lg) <= 0.f) {             // hard==0 -> adj cell = 1
                ++nzc;
                adj[(long long)(b * 8 + rl) * NND + c] = 1.0f;
            }
        }
    }

    // block reduce
#pragma unroll
    for (int off = 32; off > 0; off >>= 1) {
        uniq += __shfl_down(uniq, off);
        nzc  += __shfl_down(nzc, off);
    }
    __shared__ int scu[4], scz[4];
    __shared__ unsigned tkt;
    int wd = tid >> 6;
    if ((tid & 63) == 0) { scu[wd] = uniq; scz[wd] = nzc; }
    __syncthreads();
    if (tid == 0) {
        pcu[b] = scu[0] + scu[1] + scu[2] + scu[3];
        pcz[b] = scz[0] + scz[1] + scz[2] + scz[3];
        __threadfence();
        tkt = atomicAdd(&ctrl[5], 1u);
    }
    __syncthreads();
    if (tkt == gridDim.x - 1) {
        __threadfence();
        int t = tid;
        int4 a = ((const int4*)pcu)[t];
        int4 bq = ((const int4*)pcz)[t];
        int cu = a.x + a.y + a.z + a.w;
        int cz = bq.x + bq.y + bq.z + bq.w;
#pragma unroll
        for (int off = 32; off > 0; off >>= 1) {
            cu += __shfl_down(cu, off);
            cz += __shfl_down(cz, off);
        }
        __shared__ int rcu[4], rcz[4];
        if ((t & 63) == 0) { rcu[t >> 6] = cu; rcz[t >> 6] = cz; }
        __syncthreads();
        if (t == 0)
            rate[0] = (float)(rcz[0] + rcz[1] + rcz[2] + rcz[3]) /
                      (float)(rcu[0] + rcu[1] + rcu[2] + rcu[3]);
    }
}

extern "C" void kernel_launch(void* const* d_in, const int* in_sizes, int n_in,
                              void* d_out, int out_size, void* d_ws, size_t ws_size,
                              hipStream_t stream) {
    const float* x     = (const float*)d_in[0];
    const int*   row   = (const int*)d_in[1];
    const int*   col   = (const int*)d_in[2];
    const float* Wenc  = (const float*)d_in[3];
    const float* Wedge = (const float*)d_in[4];
    const float* bedge = (const float*)d_in[5];
    const float* noise = (const float*)d_in[6];
    const float* masku = (const float*)d_in[7];
    float* out = (float*)d_out;

    // workspace layout (~6.67 MB)
    char* ws = (char*)d_ws;
    float* xw   = (float*)(ws);                 // 4,194,304 B
    int*   slot = (int*)  (ws + 4194304);       // 8192*72*4 = 2,359,296 B
    float* u    = (float*)(ws + 6553600);       // 32 KB
    float* v    = (float*)(ws + 6586368);       // 32 KB
    int*   cnt  = (int*)  (ws + 6619136);       // 32 KB
    int*   pcu  = (int*)  (ws + 6651904);       // 4 KB
    int*   pcz  = (int*)  (ws + 6656000);       // 4 KB
    float* pmn  = (float*)(ws + 6660096);       // 4 KB
    float* pmx  = (float*)(ws + 6664192);       // 4 KB
    unsigned* ctrl = (unsigned*)(ws + 6668288); // 64 B

    float4* zq  = (float4*)(out + NF_);
    float*  adj = out + NF_;
    float* rate = out + NF_ + NN_;

    k0_init<<<32, 256, 0, stream>>>(cnt, ctrl);
    k1_mega<<<GEMMB + 1024 + 1024, 256, 0, stream>>>(x, Wenc, masku, row, col,
                                                     out, xw, cnt, slot);
    kE_spmm_uv<<<8192, 128, 0, stream>>>(xw, cnt, slot, Wedge, u, v, zq);
    kF_minmax<<<1024, 256, 0, stream>>>(row, col, u, v, bedge, pmn, pmx, ctrl, zq);
    kZ_patch<<<1024, 256, 0, stream>>>(cnt, slot, u, v, bedge, noise, adj,
                                       pcu, pcz, ctrl, rate);
}

// Round 18
// 192.582 us; speedup vs baseline: 1.2046x; 1.0271x over previous
//
#include <hip/hip_runtime.h>
#include <math.h>

// Problem constants
constexpr int NND = 8192;           // N nodes
constexpr int FD  = 512;            // features
constexpr int HD  = 128;            // hidden
constexpr int ED  = 262144;         // edges
constexpr long long NF_ = (long long)NND * FD;      // 4,194,304
constexpr long long NN_ = (long long)NND * NND;     // 67,108,864

constexpr int SLOT = 72;            // bucket capacity; max row count ~56 (7-sigma)

// zero-fill quad partition of the dense adj region (units: float4 quads)
constexpr long long Z_K1 = 0;              // feature blocks: 24*262144 = 6,291,456 (6/16)
constexpr long long Z_KD = 6291456;        // scatter blocks:  8*262144 = 2,097,152 (2/16)
constexpr long long Z_KE = 8388608;        // kE: 6*1048576 = 6,291,456 (6/16)
constexpr long long Z_KF = 14680064;       // kF: 8*262144 = 2,097,152 (ends 16,777,216)

constexpr int GEMMB = 512;                 // GEMM blocks [0,512)
constexpr int SCAT_BASE = GEMMB;           // scatter blocks [512,1536)
constexpr int FEAT_BASE = GEMMB + 1024;    // feature blocks [1536,2560)

// nontemporal float4 store (bypasses L2 allocation; for never-re-read data)
typedef float f4nt __attribute__((ext_vector_type(4)));
__device__ __forceinline__ void nt_store(float4* p, float x, float y, float z, float w) {
    f4nt v = {x, y, z, w};
    __builtin_nontemporal_store(v, (f4nt*)p);
}
__device__ __forceinline__ void nt_zero(float4* p) { nt_store(p, 0.f, 0.f, 0.f, 0.f); }

// ctrl words: [4]=ticketF, [5]=ticketZ, [8..9]=float lo/hi (written by kF)

// K0: zero cnt + ctrl.
__global__ void k0_init(int* __restrict__ cnt, unsigned* __restrict__ ctrl) {
    int t = blockIdx.x * 256 + threadIdx.x;
    if (t < NND) cnt[t] = 0;
    if (t < 16) ctrl[t] = 0u;
}

// K1: blocks [0,512)     = fp32 GEMM xw = x@W_enc, LDS-staged W/x k-tiles;
//     blocks [512,1536)  = edge scatter into row buckets + 2/16 adj fill;
//     blocks [1536,2560) = feature mask (4 quads/thread) + 6/16 adj fill.
__global__ __launch_bounds__(256) void k1_mega(const float* __restrict__ x,
                                               const float* __restrict__ W,
                                               const float* __restrict__ mask_u,
                                               const int* __restrict__ row,
                                               const int* __restrict__ col,
                                               float* __restrict__ out,
                                               float* __restrict__ xw,
                                               int* __restrict__ cnt,
                                               int* __restrict__ slot) {
    __shared__ float Wt[32 * 128];      // 16 KB: W k-tile
    __shared__ float Xt[16][36];        // 2.25 KB: x tile, stride 36 floats
                                        // (144 B = 9x16B: float4-aligned rows;
                                        //  bank (4r+kk)%32 -> 2-way max = free)
    int tid = threadIdx.x;
    if (blockIdx.x < GEMMB) {
        // ---- GEMM: block = 16 rows x 128 cols; thread = 2 rows x 4 cols ----
        // k-tiles of 32 staged in LDS; W read exactly once per block.
        int bid = blockIdx.x;
        int tx = tid & 31, ty = tid >> 5;
        int m0 = bid * 16;
        int r0 = ty * 2, r1 = r0 + 1;
        float a0[4] = {0.f, 0.f, 0.f, 0.f};
        float a1[4] = {0.f, 0.f, 0.f, 0.f};
        for (int kt = 0; kt < FD; kt += 32) {
            // stage W tile: contiguous 32*128 floats = 1024 float4
            const float4* Wq = (const float4*)(W + (long long)kt * HD);
            float4* Wtq = (float4*)Wt;
#pragma unroll
            for (int j = 0; j < 4; ++j)
                Wtq[tid + j * 256] = Wq[tid + j * 256];
            // stage x tile: 16 rows x 32 k = 128 float4
            if (tid < 128) {
                int r = tid >> 3, kq = tid & 7;
                ((float4*)&Xt[r][0])[kq] =
                    *(const float4*)(x + (long long)(m0 + r) * FD + kt + kq * 4);
            }
            __syncthreads();
#pragma unroll 8
            for (int kk = 0; kk < 32; ++kk) {
                float s0 = Xt[r0][kk], s1 = Xt[r1][kk];
                const float4 b = *(const float4*)&Wt[kk * 128 + tx * 4];
                a0[0] = fmaf(s0, b.x, a0[0]);
                a0[1] = fmaf(s0, b.y, a0[1]);
                a0[2] = fmaf(s0, b.z, a0[2]);
                a0[3] = fmaf(s0, b.w, a0[3]);
                a1[0] = fmaf(s1, b.x, a1[0]);
                a1[1] = fmaf(s1, b.y, a1[1]);
                a1[2] = fmaf(s1, b.z, a1[2]);
                a1[3] = fmaf(s1, b.w, a1[3]);
            }
            __syncthreads();
        }
        *(float4*)(xw + (long long)(m0 + r0) * HD + tx * 4) =
            make_float4(a0[0], a0[1], a0[2], a0[3]);
        *(float4*)(xw + (long long)(m0 + r1) * HD + tx * 4) =
            make_float4(a1[0], a1[1], a1[2], a1[3]);
    } else if (blockIdx.x < FEAT_BASE) {
        // ---- scatter: one edge per thread into its row bucket; +2/16 fill ----
        int e = (blockIdx.x - SCAT_BASE) * 256 + tid;   // 0 .. 262143
        int r = row[e];
        int pos = atomicAdd(&cnt[r], 1);
        slot[r * SLOT + pos] = (e << 13) | col[e];
        float4* zq = (float4*)(out + NF_);
#pragma unroll
        for (int j = 0; j < 8; ++j)
            nt_zero(&zq[Z_KD + e + (long long)j * ED]);
    } else {
        int fid = (blockIdx.x - FEAT_BASE) * 256 + tid;   // 0 .. 262143
        // column-quad = fid & 127 (stride 262144 is a multiple of 128)
        int c4 = (fid & 127) * 4;
        float kx = (mask_u[c4 + 0] < 0.2f) ? 0.f : 1.f;
        float ky = (mask_u[c4 + 1] < 0.2f) ? 0.f : 1.f;
        float kz = (mask_u[c4 + 2] < 0.2f) ? 0.f : 1.f;
        float kw = (mask_u[c4 + 3] < 0.2f) ? 0.f : 1.f;
        const float4* xq = (const float4*)x;
        float4* oq = (float4*)out;
#pragma unroll
        for (int j = 0; j < 4; ++j) {
            long long q = fid + (long long)j * 262144;
            float4 xv = xq[q];
            nt_store(&oq[q], xv.x * kx, xv.y * ky, xv.z * kz, xv.w * kw);
        }
        // 6/16 of the dense adj zero-fill
        float4* zq = (float4*)(out + NF_);
#pragma unroll
        for (int j = 0; j < 24; ++j)
            nt_zero(&zq[Z_K1 + fid + (long long)j * 262144]);
    }
}

// K_E: agg[i] = sum over bucket(i) of xw[col]; relu; u=agg@W1, v=agg@W2; +6/16 fill.
__global__ __launch_bounds__(128) void kE_spmm_uv(const float* __restrict__ xw,
                                                  const int* __restrict__ cnt,
                                                  const int* __restrict__ slot,
                                                  const float* __restrict__ Wedge,
                                                  float* __restrict__ u,
                                                  float* __restrict__ v,
                                                  float4* __restrict__ zq) {
    int i = blockIdx.x, t = threadIdx.x;
    int n = cnt[i];
    const int* sp = slot + i * SLOT;
    float acc = 0.f;
    int j = 0;
    for (; j + 4 <= n; j += 4) {
        int c0 = sp[j] & 8191, c1 = sp[j + 1] & 8191;
        int c2 = sp[j + 2] & 8191, c3 = sp[j + 3] & 8191;
        float v0 = xw[(long long)c0 * HD + t];
        float v1 = xw[(long long)c1 * HD + t];
        float v2 = xw[(long long)c2 * HD + t];
        float v3 = xw[(long long)c3 * HD + t];
        acc += v0; acc += v1; acc += v2; acc += v3;
    }
    for (; j < n; ++j) acc += xw[(long long)(sp[j] & 8191) * HD + t];
    acc = fmaxf(acc, 0.f);

    float up = acc * Wedge[t];
    float vp = acc * Wedge[HD + t];
#pragma unroll
    for (int off = 32; off > 0; off >>= 1) {
        up += __shfl_down(up, off);
        vp += __shfl_down(vp, off);
    }
    __shared__ float su[2], sv[2];
    int wid = t >> 6;
    if ((t & 63) == 0) { su[wid] = up; sv[wid] = vp; }
    __syncthreads();
    if (t == 0) { u[i] = su[0] + su[1]; v[i] = sv[0] + sv[1]; }

    // 6/16 of the dense adj zero-fill
    long long ft = (long long)i * 128 + t;
#pragma unroll
    for (int jj = 0; jj < 6; ++jj)
        nt_zero(&zq[Z_KE + ft + (long long)jj * 1048576]);
}

// K_F: edge-logit min/max only (logits recomputed in kZ, never stored);
// +2/16 fill; per-block partials; last block publishes lo/hi to ctrl[8..9].
__global__ __launch_bounds__(256) void kF_minmax(const int* __restrict__ row,
                                                 const int* __restrict__ col,
                                                 const float* __restrict__ u,
                                                 const float* __restrict__ v,
                                                 const float* __restrict__ b_edge,
                                                 float* __restrict__ pmn,
                                                 float* __restrict__ pmx,
                                                 unsigned* __restrict__ ctrl,
                                                 float4* __restrict__ zq) {
    int gid = blockIdx.x * 256 + threadIdx.x;
    float el = u[row[gid]] + v[col[gid]] + b_edge[0];

#pragma unroll
    for (int j = 0; j < 8; ++j)
        nt_zero(&zq[Z_KF + gid + (long long)j * ED]);

    float mn = el, mx = el;
#pragma unroll
    for (int off = 32; off > 0; off >>= 1) {
        mn = fminf(mn, __shfl_xor(mn, off));
        mx = fmaxf(mx, __shfl_xor(mx, off));
    }
    __shared__ float smn[4], smx[4];
    __shared__ unsigned tkt;
    int w = threadIdx.x >> 6;
    if ((threadIdx.x & 63) == 0) { smn[w] = mn; smx[w] = mx; }
    __syncthreads();
    if (threadIdx.x == 0) {
        pmn[blockIdx.x] = fminf(fminf(smn[0], smn[1]), fminf(smn[2], smn[3]));
        pmx[blockIdx.x] = fmaxf(fmaxf(smx[0], smx[1]), fmaxf(smx[2], smx[3]));
        __threadfence();
        tkt = atomicAdd(&ctrl[4], 1u);
    }
    __syncthreads();
    if (tkt == gridDim.x - 1) {
        __threadfence();
        int t = threadIdx.x;
        float4 a = ((const float4*)pmn)[t];
        float4 b = ((const float4*)pmx)[t];
        float m2 = fminf(fminf(a.x, a.y), fminf(a.z, a.w));
        float x2 = fmaxf(fmaxf(b.x, b.y), fmaxf(b.z, b.w));
#pragma unroll
        for (int off = 32; off > 0; off >>= 1) {
            m2 = fminf(m2, __shfl_xor(m2, off));
            x2 = fmaxf(x2, __shfl_xor(x2, off));
        }
        __shared__ float rmn[4], rmx[4];
        if ((t & 63) == 0) { rmn[t >> 6] = m2; rmx[t >> 6] = x2; }
        __syncthreads();
        if (t == 0) {
            float* flh = (float*)&ctrl[8];
            flh[0] = fminf(fminf(rmn[0], rmn[1]), fminf(rmn[2], rmn[3]));
            flh[1] = fmaxf(fmaxf(rmx[0], rmx[1]), fmaxf(rmx[2], rmx[3]));
        }
    }
}

// K_Z: parallel patch. Block b owns rows [8b, 8b+8); per-row buckets in LDS;
// last-edge-wins; el recomputed as u[r]+v[c]+b (bit-identical to kF's form).
__global__ __launch_bounds__(256) void kZ_patch(const int* __restrict__ cnt,
                                                const int* __restrict__ slot,
                                                const float* __restrict__ u,
                                                const float* __restrict__ v,
                                                const float* __restrict__ b_edge,
                                                const float* __restrict__ noise,
                                                float* __restrict__ adj,
                                                int* __restrict__ pcu,
                                                int* __restrict__ pcz,
                                                unsigned* __restrict__ ctrl,
                                                float* __restrict__ rate) {
    const int tid = threadIdx.x;
    const int b = blockIdx.x;
    __shared__ int skey[8 * SLOT];
    __shared__ int scnt[8];
    __shared__ float su_[8];
    if (tid < 8) {
        scnt[tid] = cnt[b * 8 + tid];
        su_[tid] = u[b * 8 + tid];
    }
    __syncthreads();
#pragma unroll
    for (int rl = 0; rl < 8; ++rl) {
        int n = scnt[rl];
        for (int i = tid; i < n; i += 256)
            skey[rl * SLOT + i] = slot[(b * 8 + rl) * SLOT + i];
    }
    __syncthreads();

    const float* flh = (const float*)&ctrl[8];
    const float lo = flh[0];
    const float hi = flh[1];
    const float kk = 0.3f / (hi - lo);          // ub=0.3, lb=0
    const float be = b_edge[0];

    int uniq = 0, nzc = 0;
#pragma unroll
    for (int rl = 0; rl < 8; ++rl) {
        int n = scnt[rl];
        const int* kp = skey + rl * SLOT;
        for (int i = tid; i < n; i += 256) {
            int key = kp[i];
            int c = key & 8191;
            // last-edge-wins: winner iff no same-col key with larger e in this row
            bool win = true;
            for (int j = 0; j < n; ++j) {
                int kj = kp[j];
                if ((kj & 8191) == c && kj > key) { win = false; break; }
            }
            if (!win) continue;
            ++uniq;
            float el = su_[rl] + v[c] + be;     // == kF's logit, bit-identical
            float pr = kk * (el - lo);
            float lp = logf(pr + 1e-10f) - log1pf(1e-10f - pr);
            float nz = noise[(long long)(b * 8 + rl) * NND + c];
            float lg = logf(nz) - log1pf(-nz);
            if ((lp + lg) <= 0.f) {             // hard==0 -> adj cell = 1
                ++nzc;
                adj[(long long)(b * 8 + rl) * NND + c] = 1.0f;
            }
        }
    }

    // block reduce
#pragma unroll
    for (int off = 32; off > 0; off >>= 1) {
        uniq += __shfl_down(uniq, off);
        nzc  += __shfl_down(nzc, off);
    }
    __shared__ int scu[4], scz[4];
    __shared__ unsigned tkt;
    int wd = tid >> 6;
    if ((tid & 63) == 0) { scu[wd] = uniq; scz[wd] = nzc; }
    __syncthreads();
    if (tid == 0) {
        pcu[b] = scu[0] + scu[1] + scu[2] + scu[3];
        pcz[b] = scz[0] + scz[1] + scz[2] + scz[3];
        __threadfence();
        tkt = atomicAdd(&ctrl[5], 1u);
    }
    __syncthreads();
    if (tkt == gridDim.x - 1) {
        __threadfence();
        int t = tid;
        int4 a = ((const int4*)pcu)[t];
        int4 bq = ((const int4*)pcz)[t];
        int cu = a.x + a.y + a.z + a.w;
        int cz = bq.x + bq.y + bq.z + bq.w;
#pragma unroll
        for (int off = 32; off > 0; off >>= 1) {
            cu += __shfl_down(cu, off);
            cz += __shfl_down(cz, off);
        }
        __shared__ int rcu[4], rcz[4];
        if ((t & 63) == 0) { rcu[t >> 6] = cu; rcz[t >> 6] = cz; }
        __syncthreads();
        if (t == 0)
            rate[0] = (float)(rcz[0] + rcz[1] + rcz[2] + rcz[3]) /
                      (float)(rcu[0] + rcu[1] + rcu[2] + rcu[3]);
    }
}

extern "C" void kernel_launch(void* const* d_in, const int* in_sizes, int n_in,
                              void* d_out, int out_size, void* d_ws, size_t ws_size,
                              hipStream_t stream) {
    const float* x     = (const float*)d_in[0];
    const int*   row   = (const int*)d_in[1];
    const int*   col   = (const int*)d_in[2];
    const float* Wenc  = (const float*)d_in[3];
    const float* Wedge = (const float*)d_in[4];
    const float* bedge = (const float*)d_in[5];
    const float* noise = (const float*)d_in[6];
    const float* masku = (const float*)d_in[7];
    float* out = (float*)d_out;

    // workspace layout (~6.67 MB)
    char* ws = (char*)d_ws;
    float* xw   = (float*)(ws);                 // 4,194,304 B
    int*   slot = (int*)  (ws + 4194304);       // 8192*72*4 = 2,359,296 B
    float* u    = (float*)(ws + 6553600);       // 32 KB
    float* v    = (float*)(ws + 6586368);       // 32 KB
    int*   cnt  = (int*)  (ws + 6619136);       // 32 KB
    int*   pcu  = (int*)  (ws + 6651904);       // 4 KB
    int*   pcz  = (int*)  (ws + 6656000);       // 4 KB
    float* pmn  = (float*)(ws + 6660096);       // 4 KB
    float* pmx  = (float*)(ws + 6664192);       // 4 KB
    unsigned* ctrl = (unsigned*)(ws + 6668288); // 64 B

    float4* zq  = (float4*)(out + NF_);
    float*  adj = out + NF_;
    float* rate = out + NF_ + NN_;

    k0_init<<<32, 256, 0, stream>>>(cnt, ctrl);
    k1_mega<<<GEMMB + 1024 + 1024, 256, 0, stream>>>(x, Wenc, masku, row, col,
                                                     out, xw, cnt, slot);
    kE_spmm_uv<<<8192, 128, 0, stream>>>(xw, cnt, slot, Wedge, u, v, zq);
    kF_minmax<<<1024, 256, 0, stream>>>(row, col, u, v, bedge, pmn, pmx, ctrl, zq);
    kZ_patch<<<1024, 256, 0, stream>>>(cnt, slot, u, v, bedge, noise, adj,
                                       pcu, pcz, ctrl, rate);
}

// Round 19
// 188.031 us; speedup vs baseline: 1.2337x; 1.0242x over previous
//
#include <hip/hip_runtime.h>
#include <math.h>

// Problem constants
constexpr int NND = 8192;           // N nodes
constexpr int FD  = 512;            // features
constexpr int HD  = 128;            // hidden
constexpr int ED  = 262144;         // edges
constexpr long long NF_ = (long long)NND * FD;      // 4,194,304
constexpr long long NN_ = (long long)NND * NND;     // 67,108,864

constexpr int SLOT = 72;            // bucket capacity; max row count ~56 (7-sigma)

// zero-fill quad partition of the dense adj region (units: float4 quads)
constexpr long long Z_K1 = 0;              // feature blocks: 24*262144 = 6,291,456 (6/16)
constexpr long long Z_KD = 6291456;        // scatter blocks:  8*262144 = 2,097,152 (2/16)
constexpr long long Z_KE = 8388608;        // kE: 6*1048576 = 6,291,456 (6/16)
constexpr long long Z_KF = 14680064;       // kF: 8*262144 = 2,097,152 (ends 16,777,216)

constexpr int GEMMB = 256;                 // GEMM blocks [0,256): 32 rows each
constexpr int SCAT_BASE = GEMMB;           // scatter blocks [256,1280)
constexpr int FEAT_BASE = GEMMB + 1024;    // feature blocks [1280,2304)

// nontemporal float4 store (bypasses L2 allocation; for never-re-read data)
typedef float f4nt __attribute__((ext_vector_type(4)));
__device__ __forceinline__ void nt_store(float4* p, float x, float y, float z, float w) {
    f4nt v = {x, y, z, w};
    __builtin_nontemporal_store(v, (f4nt*)p);
}
__device__ __forceinline__ void nt_zero(float4* p) { nt_store(p, 0.f, 0.f, 0.f, 0.f); }

// ctrl words: [4]=ticketF, [5]=ticketZ, [8..9]=float lo/hi (written by kF)

// K0: zero cnt + ctrl.
__global__ void k0_init(int* __restrict__ cnt, unsigned* __restrict__ ctrl) {
    int t = blockIdx.x * 256 + threadIdx.x;
    if (t < NND) cnt[t] = 0;
    if (t < 16) ctrl[t] = 0u;
}

// K1: blocks [0,256)     = fp32 GEMM xw = x@W_enc, LDS k-tiles, 4x4 thread tile,
//                          X transposed in LDS (b128 broadcast row-quad reads);
//     blocks [256,1280)  = edge scatter into row buckets + 2/16 adj fill;
//     blocks [1280,2304) = feature mask (4 quads/thread) + 6/16 adj fill.
__global__ __launch_bounds__(256) void k1_mega(const float* __restrict__ x,
                                               const float* __restrict__ W,
                                               const float* __restrict__ mask_u,
                                               const int* __restrict__ row,
                                               const int* __restrict__ col,
                                               float* __restrict__ out,
                                               float* __restrict__ xw,
                                               int* __restrict__ cnt,
                                               int* __restrict__ slot) {
    __shared__ float Wt[32 * 128];      // 16 KB: W k-tile [kk][col]
    __shared__ float Xt[32][36];        // 4.5 KB: x k-tile TRANSPOSED [kk][row],
                                        // stride 36 floats (144 B, 16B-aligned rows)
    int tid = threadIdx.x;
    if (blockIdx.x < GEMMB) {
        // ---- GEMM: block = 32 rows x 128 cols; thread = 4 rows x 4 cols ----
        // per kk: 1 conflict-free Wt b128 (full-bank, 2 lanes/addr) +
        //         1 broadcast Xt b128 (2 addrs/wave) -> ~20 LDS cy / 16 fma.
        int bid = blockIdx.x;
        int tx = tid & 31;              // cols tx*4 .. +3  (same Wt pattern as r12)
        int ty = tid >> 5;              // rows ty*4 .. +3
        int m0 = bid * 32;
        float a[4][4];
#pragma unroll
        for (int ri = 0; ri < 4; ++ri)
#pragma unroll
            for (int ci = 0; ci < 4; ++ci) a[ri][ci] = 0.f;
        int rs = tid >> 3;              // staging row [0,32)
        int kq = tid & 7;               // staging k-quad [0,8)
        for (int kt = 0; kt < FD; kt += 32) {
            // stage W tile: contiguous 32*128 floats = 1024 float4, 4/thread
            const float4* Wq = (const float4*)(W + (long long)kt * HD);
            float4* Wtq = (float4*)Wt;
#pragma unroll
            for (int j = 0; j < 4; ++j)
                Wtq[tid + j * 256] = Wq[tid + j * 256];
            // stage x tile transposed: 32 rows x 32 k -> Xt[kk][r], 1 quad/thread
            float4 xv = *(const float4*)(x + (long long)(m0 + rs) * FD + kt + kq * 4);
            Xt[kq * 4 + 0][rs] = xv.x;
            Xt[kq * 4 + 1][rs] = xv.y;
            Xt[kq * 4 + 2][rs] = xv.z;
            Xt[kq * 4 + 3][rs] = xv.w;
            __syncthreads();
#pragma unroll 8
            for (int kk = 0; kk < 32; ++kk) {
                float4 b = *(const float4*)&Wt[kk * 128 + tx * 4];
                float4 xr = *(const float4*)&Xt[kk][ty * 4];
                float xs[4] = {xr.x, xr.y, xr.z, xr.w};
                float bs[4] = {b.x, b.y, b.z, b.w};
#pragma unroll
                for (int ri = 0; ri < 4; ++ri)
#pragma unroll
                    for (int ci = 0; ci < 4; ++ci)
                        a[ri][ci] = fmaf(xs[ri], bs[ci], a[ri][ci]);
            }
            __syncthreads();
        }
#pragma unroll
        for (int ri = 0; ri < 4; ++ri)
            *(float4*)(xw + (long long)(m0 + ty * 4 + ri) * HD + tx * 4) =
                make_float4(a[ri][0], a[ri][1], a[ri][2], a[ri][3]);
    } else if (blockIdx.x < FEAT_BASE) {
        // ---- scatter: one edge per thread into its row bucket; +2/16 fill ----
        int e = (blockIdx.x - SCAT_BASE) * 256 + tid;   // 0 .. 262143
        int r = row[e];
        int pos = atomicAdd(&cnt[r], 1);
        slot[r * SLOT + pos] = (e << 13) | col[e];
        float4* zq = (float4*)(out + NF_);
#pragma unroll
        for (int j = 0; j < 8; ++j)
            nt_zero(&zq[Z_KD + e + (long long)j * ED]);
    } else {
        int fid = (blockIdx.x - FEAT_BASE) * 256 + tid;   // 0 .. 262143
        // column-quad = fid & 127 (stride 262144 is a multiple of 128)
        int c4 = (fid & 127) * 4;
        float kx = (mask_u[c4 + 0] < 0.2f) ? 0.f : 1.f;
        float ky = (mask_u[c4 + 1] < 0.2f) ? 0.f : 1.f;
        float kz = (mask_u[c4 + 2] < 0.2f) ? 0.f : 1.f;
        float kw = (mask_u[c4 + 3] < 0.2f) ? 0.f : 1.f;
        const float4* xq = (const float4*)x;
        float4* oq = (float4*)out;
#pragma unroll
        for (int j = 0; j < 4; ++j) {
            long long q = fid + (long long)j * 262144;
            float4 xv = xq[q];
            nt_store(&oq[q], xv.x * kx, xv.y * ky, xv.z * kz, xv.w * kw);
        }
        // 6/16 of the dense adj zero-fill
        float4* zq = (float4*)(out + NF_);
#pragma unroll
        for (int j = 0; j < 24; ++j)
            nt_zero(&zq[Z_K1 + fid + (long long)j * 262144]);
    }
}

// K_E: agg[i] = sum over bucket(i) of xw[col]; relu; u=agg@W1, v=agg@W2; +6/16 fill.
__global__ __launch_bounds__(128) void kE_spmm_uv(const float* __restrict__ xw,
                                                  const int* __restrict__ cnt,
                                                  const int* __restrict__ slot,
                                                  const float* __restrict__ Wedge,
                                                  float* __restrict__ u,
                                                  float* __restrict__ v,
                                                  float4* __restrict__ zq) {
    int i = blockIdx.x, t = threadIdx.x;
    int n = cnt[i];
    const int* sp = slot + i * SLOT;
    float acc = 0.f;
    int j = 0;
    for (; j + 4 <= n; j += 4) {
        int c0 = sp[j] & 8191, c1 = sp[j + 1] & 8191;
        int c2 = sp[j + 2] & 8191, c3 = sp[j + 3] & 8191;
        float v0 = xw[(long long)c0 * HD + t];
        float v1 = xw[(long long)c1 * HD + t];
        float v2 = xw[(long long)c2 * HD + t];
        float v3 = xw[(long long)c3 * HD + t];
        acc += v0; acc += v1; acc += v2; acc += v3;
    }
    for (; j < n; ++j) acc += xw[(long long)(sp[j] & 8191) * HD + t];
    acc = fmaxf(acc, 0.f);

    float up = acc * Wedge[t];
    float vp = acc * Wedge[HD + t];
#pragma unroll
    for (int off = 32; off > 0; off >>= 1) {
        up += __shfl_down(up, off);
        vp += __shfl_down(vp, off);
    }
    __shared__ float su[2], sv[2];
    int wid = t >> 6;
    if ((t & 63) == 0) { su[wid] = up; sv[wid] = vp; }
    __syncthreads();
    if (t == 0) { u[i] = su[0] + su[1]; v[i] = sv[0] + sv[1]; }

    // 6/16 of the dense adj zero-fill
    long long ft = (long long)i * 128 + t;
#pragma unroll
    for (int jj = 0; jj < 6; ++jj)
        nt_zero(&zq[Z_KE + ft + (long long)jj * 1048576]);
}

// K_F: edge-logit min/max only (logits recomputed in kZ, never stored);
// +2/16 fill; per-block partials; last block publishes lo/hi to ctrl[8..9].
__global__ __launch_bounds__(256) void kF_minmax(const int* __restrict__ row,
                                                 const int* __restrict__ col,
                                                 const float* __restrict__ u,
                                                 const float* __restrict__ v,
                                                 const float* __restrict__ b_edge,
                                                 float* __restrict__ pmn,
                                                 float* __restrict__ pmx,
                                                 unsigned* __restrict__ ctrl,
                                                 float4* __restrict__ zq) {
    int gid = blockIdx.x * 256 + threadIdx.x;
    float el = u[row[gid]] + v[col[gid]] + b_edge[0];

#pragma unroll
    for (int j = 0; j < 8; ++j)
        nt_zero(&zq[Z_KF + gid + (long long)j * ED]);

    float mn = el, mx = el;
#pragma unroll
    for (int off = 32; off > 0; off >>= 1) {
        mn = fminf(mn, __shfl_xor(mn, off));
        mx = fmaxf(mx, __shfl_xor(mx, off));
    }
    __shared__ float smn[4], smx[4];
    __shared__ unsigned tkt;
    int w = threadIdx.x >> 6;
    if ((threadIdx.x & 63) == 0) { smn[w] = mn; smx[w] = mx; }
    __syncthreads();
    if (threadIdx.x == 0) {
        pmn[blockIdx.x] = fminf(fminf(smn[0], smn[1]), fminf(smn[2], smn[3]));
        pmx[blockIdx.x] = fmaxf(fmaxf(smx[0], smx[1]), fmaxf(smx[2], smx[3]));
        __threadfence();
        tkt = atomicAdd(&ctrl[4], 1u);
    }
    __syncthreads();
    if (tkt == gridDim.x - 1) {
        __threadfence();
        int t = threadIdx.x;
        float4 a = ((const float4*)pmn)[t];
        float4 b = ((const float4*)pmx)[t];
        float m2 = fminf(fminf(a.x, a.y), fminf(a.z, a.w));
        float x2 = fmaxf(fmaxf(b.x, b.y), fmaxf(b.z, b.w));
#pragma unroll
        for (int off = 32; off > 0; off >>= 1) {
            m2 = fminf(m2, __shfl_xor(m2, off));
            x2 = fmaxf(x2, __shfl_xor(x2, off));
        }
        __shared__ float rmn[4], rmx[4];
        if ((t & 63) == 0) { rmn[t >> 6] = m2; rmx[t >> 6] = x2; }
        __syncthreads();
        if (t == 0) {
            float* flh = (float*)&ctrl[8];
            flh[0] = fminf(fminf(rmn[0], rmn[1]), fminf(rmn[2], rmn[3]));
            flh[1] = fmaxf(fmaxf(rmx[0], rmx[1]), fmaxf(rmx[2], rmx[3]));
        }
    }
}

// K_Z: parallel patch. Block b owns rows [8b, 8b+8); per-row buckets in LDS;
// last-edge-wins; el recomputed as u[r]+v[c]+b (bit-identical to kF's form).
__global__ __launch_bounds__(256) void kZ_patch(const int* __restrict__ cnt,
                                                const int* __restrict__ slot,
                                                const float* __restrict__ u,
                                                const float* __restrict__ v,
                                                const float* __restrict__ b_edge,
                                                const float* __restrict__ noise,
                                                float* __restrict__ adj,
                                                int* __restrict__ pcu,
                                                int* __restrict__ pcz,
                                                unsigned* __restrict__ ctrl,
                                                float* __restrict__ rate) {
    const int tid = threadIdx.x;
    const int b = blockIdx.x;
    __shared__ int skey[8 * SLOT];
    __shared__ int scnt[8];
    __shared__ float su_[8];
    if (tid < 8) {
        scnt[tid] = cnt[b * 8 + tid];
        su_[tid] = u[b * 8 + tid];
    }
    __syncthreads();
#pragma unroll
    for (int rl = 0; rl < 8; ++rl) {
        int n = scnt[rl];
        for (int i = tid; i < n; i += 256)
            skey[rl * SLOT + i] = slot[(b * 8 + rl) * SLOT + i];
    }
    __syncthreads();

    const float* flh = (const float*)&ctrl[8];
    const float lo = flh[0];
    const float hi = flh[1];
    const float kk = 0.3f / (hi - lo);          // ub=0.3, lb=0
    const float be = b_edge[0];

    int uniq = 0, nzc = 0;
#pragma unroll
    for (int rl = 0; rl < 8; ++rl) {
        int n = scnt[rl];
        const int* kp = skey + rl * SLOT;
        for (int i = tid; i < n; i += 256) {
            int key = kp[i];
            int c = key & 8191;
            // last-edge-wins: winner iff no same-col key with larger e in this row
            bool win = true;
            for (int j = 0; j < n; ++j) {
                int kj = kp[j];
                if ((kj & 8191) == c && kj > key) { win = false; break; }
            }
            if (!win) continue;
            ++uniq;
            float el = su_[rl] + v[c] + be;     // == kF's logit, bit-identical
            float pr = kk * (el - lo);
            float lp = logf(pr + 1e-10f) - log1pf(1e-10f - pr);
            float nz = noise[(long long)(b * 8 + rl) * NND + c];
            float lg = logf(nz) - log1pf(-nz);
            if ((lp + lg) <= 0.f) {             // hard==0 -> adj cell = 1
                ++nzc;
                adj[(long long)(b * 8 + rl) * NND + c] = 1.0f;
            }
        }
    }

    // block reduce
#pragma unroll
    for (int off = 32; off > 0; off >>= 1) {
        uniq += __shfl_down(uniq, off);
        nzc  += __shfl_down(nzc, off);
    }
    __shared__ int scu[4], scz[4];
    __shared__ unsigned tkt;
    int wd = tid >> 6;
    if ((tid & 63) == 0) { scu[wd] = uniq; scz[wd] = nzc; }
    __syncthreads();
    if (tid == 0) {
        pcu[b] = scu[0] + scu[1] + scu[2] + scu[3];
        pcz[b] = scz[0] + scz[1] + scz[2] + scz[3];
        __threadfence();
        tkt = atomicAdd(&ctrl[5], 1u);
    }
    __syncthreads();
    if (tkt == gridDim.x - 1) {
        __threadfence();
        int t = tid;
        int4 a = ((const int4*)pcu)[t];
        int4 bq = ((const int4*)pcz)[t];
        int cu = a.x + a.y + a.z + a.w;
        int cz = bq.x + bq.y + bq.z + bq.w;
#pragma unroll
        for (int off = 32; off > 0; off >>= 1) {
            cu += __shfl_down(cu, off);
            cz += __shfl_down(cz, off);
        }
        __shared__ int rcu[4], rcz[4];
        if ((t & 63) == 0) { rcu[t >> 6] = cu; rcz[t >> 6] = cz; }
        __syncthreads();
        if (t == 0)
            rate[0] = (float)(rcz[0] + rcz[1] + rcz[2] + rcz[3]) /
                      (float)(rcu[0] + rcu[1] + rcu[2] + rcu[3]);
    }
}

extern "C" void kernel_launch(void* const* d_in, const int* in_sizes, int n_in,
                              void* d_out, int out_size, void* d_ws, size_t ws_size,
                              hipStream_t stream) {
    const float* x     = (const float*)d_in[0];
    const int*   row   = (const int*)d_in[1];
    const int*   col   = (const int*)d_in[2];
    const float* Wenc  = (const float*)d_in[3];
    const float* Wedge = (const float*)d_in[4];
    const float* bedge = (const float*)d_in[5];
    const float* noise = (const float*)d_in[6];
    const float* masku = (const float*)d_in[7];
    float* out = (float*)d_out;

    // workspace layout (~6.67 MB)
    char* ws = (char*)d_ws;
    float* xw   = (float*)(ws);                 // 4,194,304 B
    int*   slot = (int*)  (ws + 4194304);       // 8192*72*4 = 2,359,296 B
    float* u    = (float*)(ws + 6553600);       // 32 KB
    float* v    = (float*)(ws + 6586368);       // 32 KB
    int*   cnt  = (int*)  (ws + 6619136);       // 32 KB
    int*   pcu  = (int*)  (ws + 6651904);       // 4 KB
    int*   pcz  = (int*)  (ws + 6656000);       // 4 KB
    float* pmn  = (float*)(ws + 6660096);       // 4 KB
    float* pmx  = (float*)(ws + 6664192);       // 4 KB
    unsigned* ctrl = (unsigned*)(ws + 6668288); // 64 B

    float4* zq  = (float4*)(out + NF_);
    float*  adj = out + NF_;
    float* rate = out + NF_ + NN_;

    k0_init<<<32, 256, 0, stream>>>(cnt, ctrl);
    k1_mega<<<GEMMB + 1024 + 1024, 256, 0, stream>>>(x, Wenc, masku, row, col,
                                                     out, xw, cnt, slot);
    kE_spmm_uv<<<8192, 128, 0, stream>>>(xw, cnt, slot, Wedge, u, v, zq);
    kF_minmax<<<1024, 256, 0, stream>>>(row, col, u, v, bedge, pmn, pmx, ctrl, zq);
    kZ_patch<<<1024, 256, 0, stream>>>(cnt, slot, u, v, bedge, noise, adj,
                                       pcu, pcz, ctrl, rate);
}